// Round 1
// baseline (413.614 us; speedup 1.0000x reference)
//
#include <hip/hip_runtime.h>
#include <hip/hip_bf16.h>
#include <stdint.h>

// Problem constants
#define D_MODEL 1024
#define NHEADS  16
#define DKH     64
#define BATCH   4
#define SEQ     2048
#define NTOK    (BATCH * SEQ)   // 8192

typedef unsigned short u16;
using bf16x8 = __attribute__((ext_vector_type(8))) short;   // 8 bf16 = 4 VGPR (MFMA A/B frag)
using f32x4  = __attribute__((ext_vector_type(4))) float;   // MFMA C/D frag

// async global->LDS, 16B per lane; LDS dest must be wave-uniform base (+lane*16 by HW)
#define GLD16(g, l)                                                            \
  __builtin_amdgcn_global_load_lds(                                            \
      (const __attribute__((address_space(1))) void*)(g),                      \
      (__attribute__((address_space(3))) void*)(l), 16, 0, 0)

__device__ inline u16 f2bf(float f) {
  __hip_bfloat16 h = __float2bfloat16(f);
  return __builtin_bit_cast(u16, h);
}

// ---------------------------------------------------------------- converts
__global__ __launch_bounds__(256) void cvt_f32_bf16(const float* __restrict__ src,
                                                    u16* __restrict__ dst, int n4) {
  int i = blockIdx.x * 256 + threadIdx.x;
  if (i >= n4) return;
  float4 v = reinterpret_cast<const float4*>(src)[i];
  ushort4 o = make_ushort4(f2bf(v.x), f2bf(v.y), f2bf(v.z), f2bf(v.w));
  reinterpret_cast<ushort4*>(dst)[i] = o;
}

// ---------------------------------------------------------------- GEMM C = A * B^T
// A [M,K] bf16 row-major, B [N,K] bf16 row-major (nn.Linear weight layout), C [M,N]
// m97 structure: 128x128 tile, BK=64, 4 waves (2x2), global_load_lds width 16.
template <int OUT_BF16>
__global__ __launch_bounds__(256) void gemm_bt(const u16* __restrict__ A,
                                               const u16* __restrict__ B,
                                               void* __restrict__ Cv,
                                               int M, int N, int K) {
  __shared__ u16 As[128 * 64];
  __shared__ u16 Bs[128 * 64];
  const int t = threadIdx.x, lane = t & 63, wave = t >> 6;
  const int wr = wave >> 1, wc = wave & 1;
  const int frow = lane & 15, fk = (lane >> 4) * 8;
  const int bM = blockIdx.y * 128, bN = blockIdx.x * 128;

  f32x4 acc[4][4] = {};

  for (int k0 = 0; k0 < K; k0 += 64) {
    __syncthreads();  // prev compute done before overwrite
#pragma unroll
    for (int p = 0; p < 4; ++p) {  // 1024 16B-chunks per 128x64 tile, 256 thr -> 4 passes
      int chunk = p * 256 + t;
      int r = chunk >> 3, c = chunk & 7;
      GLD16(A + (size_t)(bM + r) * K + k0 + c * 8, As + (size_t)(p * 256 + (t & ~63)) * 8);
      GLD16(B + (size_t)(bN + r) * K + k0 + c * 8, Bs + (size_t)(p * 256 + (t & ~63)) * 8);
    }
    __syncthreads();  // compiler drains vmcnt before barrier -> staging visible

    bf16x8 a[2][4], b[2][4];
#pragma unroll
    for (int kk = 0; kk < 2; ++kk) {
#pragma unroll
      for (int m = 0; m < 4; ++m)
        a[kk][m] = *(const bf16x8*)&As[(wr * 64 + m * 16 + frow) * 64 + kk * 32 + fk];
#pragma unroll
      for (int n = 0; n < 4; ++n)
        b[kk][n] = *(const bf16x8*)&Bs[(wc * 64 + n * 16 + frow) * 64 + kk * 32 + fk];
    }
#pragma unroll
    for (int kk = 0; kk < 2; ++kk)
#pragma unroll
      for (int m = 0; m < 4; ++m)
#pragma unroll
        for (int n = 0; n < 4; ++n)
          acc[m][n] = __builtin_amdgcn_mfma_f32_16x16x32_bf16(a[kk][m], b[kk][n], acc[m][n], 0, 0, 0);
  }

  // epilogue: D layout col = lane&15, row = (lane>>4)*4 + j
  const int r0 = bM + wr * 64 + (lane >> 4) * 4;
  const int c0 = bN + wc * 64 + (lane & 15);
#pragma unroll
  for (int m = 0; m < 4; ++m)
#pragma unroll
    for (int n = 0; n < 4; ++n)
#pragma unroll
      for (int j = 0; j < 4; ++j) {
        size_t idx = (size_t)(r0 + m * 16 + j) * N + (c0 + n * 16);
        if (OUT_BF16)
          ((u16*)Cv)[idx] = f2bf(acc[m][n][j]);
        else
          ((float*)Cv)[idx] = acc[m][n][j];
      }
}

// ---------------------------------------------------------------- flash attention (causal)
// Q,K,V,O: bf16 [NTOK, D_MODEL]; head h occupies cols h*64..h*64+63.
// Block: 128 q-rows for one (b,h); 4 waves x 32 q-rows; KV tiles of 64.
__global__ __launch_bounds__(256) void attn_fwd(const u16* __restrict__ Q,
                                                const u16* __restrict__ K,
                                                const u16* __restrict__ V,
                                                u16* __restrict__ O) {
  __shared__ u16 Kl[64 * 64];       // K tile, chunk-XOR swizzled (bank-conflict-free reads)
  __shared__ u16 Vt[64 * 88];       // V^T tile [dk][kv], padded stride 88 (176B, 16B-mult)
  __shared__ u16 Pl[4][32 * 88];    // per-wave P tile [q][kv], padded stride 88

  const int t = threadIdx.x, lane = t & 63, wave = t >> 6;
  const int frow = lane & 15, fk = (lane >> 4) * 8;
  const int q0 = blockIdx.x * 128;
  const int b = blockIdx.y >> 4, h = blockIdx.y & 15;
  const size_t rowbase = (size_t)b * SEQ;
  const int hcol = h * 64;
  const int qw = q0 + wave * 32;
  u16* pw = &Pl[wave][0];

  // Q fragments held in registers for the whole kernel
  bf16x8 qf[2][2];
#pragma unroll
  for (int m = 0; m < 2; ++m)
#pragma unroll
    for (int kk = 0; kk < 2; ++kk)
      qf[m][kk] = *(const bf16x8*)&Q[(rowbase + qw + m * 16 + frow) * D_MODEL + hcol + kk * 32 + fk];

  f32x4 o_acc[2][4] = {};
  float mstate[2][4], lstate[2][4];
#pragma unroll
  for (int m = 0; m < 2; ++m)
#pragma unroll
    for (int j = 0; j < 4; ++j) { mstate[m][j] = -__builtin_inff(); lstate[m][j] = 0.f; }

  const int kv_end = q0 + 128;  // causal bound for this block
  for (int kv0 = 0; kv0 < kv_end; kv0 += 64) {
    __syncthreads();  // prev tile's LDS reads done
    // stage K tile, source-chunk XOR so swizzled reads are conflict-free
#pragma unroll
    for (int p = 0; p < 2; ++p) {
      int chunk = p * 256 + t;
      int r = chunk >> 3, c = chunk & 7;
      int csrc = c ^ (r & 7);
      GLD16(K + (rowbase + kv0 + r) * D_MODEL + hcol + csrc * 8,
            Kl + (size_t)(p * 256 + (t & ~63)) * 8);
    }
    // stage V transposed (reg round-trip, scalar b16 scatter)
#pragma unroll
    for (int p = 0; p < 2; ++p) {
      int chunk = p * 256 + t;
      int r = chunk >> 3, c = chunk & 7;
      uint4 v = *(const uint4*)&V[(rowbase + kv0 + r) * D_MODEL + hcol + c * 8];
      unsigned vv[4] = {v.x, v.y, v.z, v.w};
#pragma unroll
      for (int i = 0; i < 4; ++i) {
        Vt[(c * 8 + 2 * i) * 88 + r]     = (u16)(vv[i] & 0xffff);
        Vt[(c * 8 + 2 * i + 1) * 88 + r] = (u16)(vv[i] >> 16);
      }
    }
    __syncthreads();  // staging visible (vmcnt+lgkmcnt drained by barrier)

    if (kv0 <= qw + 31) {  // wave-uniform causal skip
      // ---- S = Q K^T
      f32x4 s[2][4] = {};
      bf16x8 kf[4][2];
#pragma unroll
      for (int n = 0; n < 4; ++n)
#pragma unroll
        for (int kk = 0; kk < 2; ++kk) {
          int row = n * 16 + frow;
          kf[n][kk] = *(const bf16x8*)&Kl[row * 64 + (((kk * 4 + (lane >> 4)) ^ (row & 7)) * 8)];
        }
#pragma unroll
      for (int kk = 0; kk < 2; ++kk)
#pragma unroll
        for (int m = 0; m < 2; ++m)
#pragma unroll
          for (int n = 0; n < 4; ++n)
            s[m][n] = __builtin_amdgcn_mfma_f32_16x16x32_bf16(qf[m][kk], kf[n][kk], s[m][n], 0, 0, 0);

      // ---- online softmax (row = (lane>>4)*4+j, col = lane&15; 16-lane shfl reduce)
      float alpha[2][4];
#pragma unroll
      for (int m = 0; m < 2; ++m)
#pragma unroll
        for (int j = 0; j < 4; ++j) {
          const int qg = qw + m * 16 + (lane >> 4) * 4 + j;
          float rmax = -__builtin_inff();
#pragma unroll
          for (int n = 0; n < 4; ++n) {
            float v = s[m][n][j] * 0.125f;  // 1/sqrt(64)
            int kg = kv0 + n * 16 + (lane & 15);
            if (kg > qg) v = -__builtin_inff();
            s[m][n][j] = v;
            rmax = fmaxf(rmax, v);
          }
#pragma unroll
          for (int off = 1; off < 16; off <<= 1) rmax = fmaxf(rmax, __shfl_xor(rmax, off));
          float mnew = fmaxf(mstate[m][j], rmax);
          float al = (mnew <= -1e30f) ? 1.0f : __expf(mstate[m][j] - mnew);
          float rsum = 0.f;
#pragma unroll
          for (int n = 0; n < 4; ++n) {
            float pv = (s[m][n][j] <= -1e30f) ? 0.0f : __expf(s[m][n][j] - mnew);
            pw[(m * 16 + (lane >> 4) * 4 + j) * 88 + n * 16 + (lane & 15)] = f2bf(pv);
            rsum += pv;
          }
#pragma unroll
          for (int off = 1; off < 16; off <<= 1) rsum += __shfl_xor(rsum, off);
          lstate[m][j] = lstate[m][j] * al + rsum;
          mstate[m][j] = mnew;
          alpha[m][j] = al;
        }
      // rescale O
#pragma unroll
      for (int m = 0; m < 2; ++m)
#pragma unroll
        for (int d = 0; d < 4; ++d)
#pragma unroll
          for (int j = 0; j < 4; ++j) o_acc[m][d][j] *= alpha[m][j];

      // ---- O += P V   (P from per-wave LDS, V^T from padded LDS)
      bf16x8 pf[2][2], vf[4][2];
#pragma unroll
      for (int m = 0; m < 2; ++m)
#pragma unroll
        for (int kk = 0; kk < 2; ++kk)
          pf[m][kk] = *(const bf16x8*)&pw[(m * 16 + frow) * 88 + kk * 32 + fk];
#pragma unroll
      for (int d = 0; d < 4; ++d)
#pragma unroll
        for (int kk = 0; kk < 2; ++kk)
          vf[d][kk] = *(const bf16x8*)&Vt[(d * 16 + frow) * 88 + kk * 32 + fk];
#pragma unroll
      for (int kk = 0; kk < 2; ++kk)
#pragma unroll
        for (int m = 0; m < 2; ++m)
#pragma unroll
          for (int d = 0; d < 4; ++d)
            o_acc[m][d] = __builtin_amdgcn_mfma_f32_16x16x32_bf16(pf[m][kk], vf[d][kk], o_acc[m][d], 0, 0, 0);
    }
  }

  // ---- epilogue: O /= l, write bf16 [NTOK, D_MODEL]
#pragma unroll
  for (int m = 0; m < 2; ++m)
#pragma unroll
    for (int j = 0; j < 4; ++j) {
      float inv = 1.0f / lstate[m][j];
#pragma unroll
      for (int d = 0; d < 4; ++d)
        O[(rowbase + qw + m * 16 + (lane >> 4) * 4 + j) * D_MODEL + hcol + d * 16 + (lane & 15)] =
            f2bf(o_acc[m][d][j] * inv);
    }
}

// ---------------------------------------------------------------- launch
extern "C" void kernel_launch(void* const* d_in, const int* in_sizes, int n_in,
                              void* d_out, int out_size, void* d_ws, size_t ws_size,
                              hipStream_t stream) {
  const float* x  = (const float*)d_in[0];
  const float* Wq = (const float*)d_in[1];
  const float* Wk = (const float*)d_in[2];
  const float* Wv = (const float*)d_in[3];
  const float* Wo = (const float*)d_in[4];
  float* out = (float*)d_out;

  u16* ws  = (u16*)d_ws;
  u16* xb  = ws;                                  // [NTOK, D] bf16 (reused as attn-out later)
  u16* wqb = xb + (size_t)NTOK * D_MODEL;
  u16* wkb = wqb + (size_t)D_MODEL * D_MODEL;
  u16* wvb = wkb + (size_t)D_MODEL * D_MODEL;
  u16* wob = wvb + (size_t)D_MODEL * D_MODEL;
  u16* Qb  = wob + (size_t)D_MODEL * D_MODEL;
  u16* Kb  = Qb + (size_t)NTOK * D_MODEL;
  u16* Vb  = Kb + (size_t)NTOK * D_MODEL;
  u16* Ob  = xb;  // reuse x's bf16 buffer once projections are done

  // converts
  cvt_f32_bf16<<<(NTOK * D_MODEL / 4) / 256, 256, 0, stream>>>(x, xb, NTOK * D_MODEL / 4);
  cvt_f32_bf16<<<(D_MODEL * D_MODEL / 4) / 256, 256, 0, stream>>>(Wq, wqb, D_MODEL * D_MODEL / 4);
  cvt_f32_bf16<<<(D_MODEL * D_MODEL / 4) / 256, 256, 0, stream>>>(Wk, wkb, D_MODEL * D_MODEL / 4);
  cvt_f32_bf16<<<(D_MODEL * D_MODEL / 4) / 256, 256, 0, stream>>>(Wv, wvb, D_MODEL * D_MODEL / 4);
  cvt_f32_bf16<<<(D_MODEL * D_MODEL / 4) / 256, 256, 0, stream>>>(Wo, wob, D_MODEL * D_MODEL / 4);

  // QKV projections
  dim3 gproj(D_MODEL / 128, NTOK / 128);  // (8, 64)
  gemm_bt<1><<<gproj, 256, 0, stream>>>(xb, wqb, Qb, NTOK, D_MODEL, D_MODEL);
  gemm_bt<1><<<gproj, 256, 0, stream>>>(xb, wkb, Kb, NTOK, D_MODEL, D_MODEL);
  gemm_bt<1><<<gproj, 256, 0, stream>>>(xb, wvb, Vb, NTOK, D_MODEL, D_MODEL);

  // causal flash attention
  attn_fwd<<<dim3(SEQ / 128, BATCH * NHEADS), 256, 0, stream>>>(Qb, Kb, Vb, Ob);

  // output projection (f32 out)
  gemm_bt<0><<<gproj, 256, 0, stream>>>(Ob, wob, out, NTOK, D_MODEL, D_MODEL);
}

// Round 2
// 229.149 us; speedup vs baseline: 1.8050x; 1.8050x over previous
//
#include <hip/hip_runtime.h>
#include <hip/hip_bf16.h>
#include <stdint.h>

// Problem constants
#define D_MODEL 1024
#define NHEADS  16
#define DKH     64
#define BATCH   4
#define SEQ     2048
#define NTOK    (BATCH * SEQ)   // 8192

typedef unsigned short u16;
using bf16x8 = __attribute__((ext_vector_type(8))) short;   // 8 bf16 = 4 VGPR (MFMA A/B frag)
using f32x4  = __attribute__((ext_vector_type(4))) float;   // MFMA C/D frag

// async global->LDS, 16B per lane; LDS dest is wave-uniform base (+lane*16 by HW)
#define GLD16(g, l)                                                            \
  __builtin_amdgcn_global_load_lds(                                            \
      (const __attribute__((address_space(1))) void*)(g),                      \
      (__attribute__((address_space(3))) void*)(l), 16, 0, 0)

__device__ inline u16 f2bf(float f) {
  __hip_bfloat16 h = __float2bfloat16(f);
  return __builtin_bit_cast(u16, h);
}

// ---------------------------------------------------------------- converts
__global__ __launch_bounds__(256) void cvt_f32_bf16(const float* __restrict__ src,
                                                    u16* __restrict__ dst, int n4) {
  int i = blockIdx.x * 256 + threadIdx.x;
  if (i >= n4) return;
  float4 v = reinterpret_cast<const float4*>(src)[i];
  ushort4 o = make_ushort4(f2bf(v.x), f2bf(v.y), f2bf(v.z), f2bf(v.w));
  reinterpret_cast<ushort4*>(dst)[i] = o;
}

// ---------------------------------------------------------------- GEMM C = A * B^T
// A [M,K] bf16 row-major, B [N,K] bf16 row-major, C [M,N]
// MODE 0: f32 out. MODE 1: bf16 out. MODE 3: bf16 out scaled by 0.125 (Q proj).
// MODE 2: bf16 out TRANSPOSED per-head: Vt[(tok/SEQ)*D_MODEL + col][tok%SEQ]
template <int MODE>
__global__ __launch_bounds__(256) void gemm_bt(const u16* __restrict__ A,
                                               const u16* __restrict__ B,
                                               void* __restrict__ Cv,
                                               int M, int N, int K) {
  __shared__ u16 As[128 * 64];
  __shared__ u16 Bs[128 * 64];
  const int t = threadIdx.x, lane = t & 63, wave = t >> 6;
  const int wr = wave >> 1, wc = wave & 1;
  const int frow = lane & 15, fk = (lane >> 4) * 8;
  const int bM = blockIdx.y * 128, bN = blockIdx.x * 128;

  f32x4 acc[4][4] = {};

  for (int k0 = 0; k0 < K; k0 += 64) {
    __syncthreads();
#pragma unroll
    for (int p = 0; p < 4; ++p) {
      int chunk = p * 256 + t;
      int r = chunk >> 3, c = chunk & 7;
      GLD16(A + (size_t)(bM + r) * K + k0 + c * 8, As + (size_t)(p * 256 + (t & ~63)) * 8);
      GLD16(B + (size_t)(bN + r) * K + k0 + c * 8, Bs + (size_t)(p * 256 + (t & ~63)) * 8);
    }
    __syncthreads();

    bf16x8 a[2][4], b[2][4];
#pragma unroll
    for (int kk = 0; kk < 2; ++kk) {
#pragma unroll
      for (int m = 0; m < 4; ++m)
        a[kk][m] = *(const bf16x8*)&As[(wr * 64 + m * 16 + frow) * 64 + kk * 32 + fk];
#pragma unroll
      for (int n = 0; n < 4; ++n)
        b[kk][n] = *(const bf16x8*)&Bs[(wc * 64 + n * 16 + frow) * 64 + kk * 32 + fk];
    }
#pragma unroll
    for (int kk = 0; kk < 2; ++kk)
#pragma unroll
      for (int m = 0; m < 4; ++m)
#pragma unroll
        for (int n = 0; n < 4; ++n)
          acc[m][n] = __builtin_amdgcn_mfma_f32_16x16x32_bf16(a[kk][m], b[kk][n], acc[m][n], 0, 0, 0);
  }

  const int r0 = bM + wr * 64 + (lane >> 4) * 4;
  const int c0 = bN + wc * 64 + (lane & 15);
#pragma unroll
  for (int m = 0; m < 4; ++m)
#pragma unroll
    for (int n = 0; n < 4; ++n) {
      if (MODE == 2) {
        int r = r0 + m * 16;        // token (4-aligned; j=0..3 stays in one batch)
        int cc = c0 + n * 16;       // d_model column
        size_t off = ((size_t)(r >> 11) * D_MODEL + cc) * SEQ + (r & (SEQ - 1));
        ushort4 o4 = make_ushort4(f2bf(acc[m][n][0]), f2bf(acc[m][n][1]),
                                  f2bf(acc[m][n][2]), f2bf(acc[m][n][3]));
        *(ushort4*)((u16*)Cv + off) = o4;
      } else {
#pragma unroll
        for (int j = 0; j < 4; ++j) {
          size_t idx = (size_t)(r0 + m * 16 + j) * N + (c0 + n * 16);
          float v = acc[m][n][j];
          if (MODE == 3) v *= 0.125f;  // 1/sqrt(Dk), exact in bf16
          if (MODE == 0)
            ((float*)Cv)[idx] = v;
          else
            ((u16*)Cv)[idx] = f2bf(v);
        }
      }
    }
}

// ---------------------------------------------------------------- flash attention (causal)
// Q (pre-scaled by 0.125), K: bf16 [NTOK, D_MODEL]; Vt: bf16 [B*H*64][SEQ] (per-head V^T)
// O: bf16 [NTOK, D_MODEL]. Block = 128 q rows of one (b,h); 4 waves x 32 q rows; KV tile 64.
// Swapped QK^T (S^T) so softmax k-reduce is lane-local + 2 shfl; PV computed as O^T.
__global__ __launch_bounds__(256) void attn_fwd(const u16* __restrict__ Q,
                                                const u16* __restrict__ K,
                                                const u16* __restrict__ Vt,
                                                u16* __restrict__ O) {
  __shared__ u16 Kl[2][64 * 64];   // K tile, XOR-swizzled via pre-swizzled global src
  __shared__ u16 Vl[2][64 * 64];   // V^T tile, same swizzle
  __shared__ u16 Pl[4][32 * 64];   // per-wave P[q][k], XOR-swizzled

  const int t = threadIdx.x, lane = t & 63, wave = t >> 6;
  const int c = lane & 15, g = lane >> 4;
  const int bh = blockIdx.x & 63;           // bh fastest -> heavy tiles spread over XCDs
  const int qtile = 15 - (blockIdx.x >> 6); // heavy-first dispatch
  const int q0 = qtile * 128;
  const size_t rowbase = (size_t)(bh >> 4) * SEQ;
  const int hcol = (bh & 15) * DKH;
  const int qw = q0 + wave * 32;
  u16* pw = Pl[wave];
  const int nit = qtile * 2 + 2;            // kv tiles: kv0 < q0+128

  auto stage = [&](int buf, int kv0) {
#pragma unroll
    for (int p = 0; p < 2; ++p) {
      int chunk = p * 256 + t;
      int r = chunk >> 3, cc = chunk & 7;
      int cs = cc ^ (r & 7);  // pre-swizzle global source; LDS stays linear
      GLD16(K + (rowbase + kv0 + r) * D_MODEL + hcol + cs * 8,
            &Kl[buf][(size_t)(p * 256 + (t & ~63)) * 8]);
      GLD16(Vt + ((size_t)bh * DKH + r) * SEQ + kv0 + cs * 8,
            &Vl[buf][(size_t)(p * 256 + (t & ~63)) * 8]);
    }
  };

  stage(0, 0);

  // Q fragments in registers for the whole kernel (Q pre-scaled by 1/8)
  bf16x8 qf[2][2];
#pragma unroll
  for (int m = 0; m < 2; ++m)
#pragma unroll
    for (int kk = 0; kk < 2; ++kk)
      qf[m][kk] = *(const bf16x8*)&Q[(rowbase + qw + m * 16 + c) * D_MODEL + hcol + kk * 32 + g * 8];

  f32x4 ot[4][2] = {};                         // O^T[d_local][q]: row d=g*4+jj, col q=m*16+c
  float mstate[2] = {-__builtin_inff(), -__builtin_inff()};
  float lstate[2] = {0.f, 0.f};

  __syncthreads();
  int cur = 0;
  for (int it = 0; it < nit; ++it) {
    const int kv0 = it * 64;
    if (it + 1 < nit) stage(cur ^ 1, kv0 + 64);  // prefetch overlaps compute

    if (kv0 <= qw + 31) {  // wave-uniform causal participation
      // ---- S^T = K Q^T : rows k, cols q (swapped operands)
      bf16x8 kf[4][2];
#pragma unroll
      for (int n = 0; n < 4; ++n)
#pragma unroll
        for (int kk = 0; kk < 2; ++kk)
          kf[n][kk] = *(const bf16x8*)&Kl[cur][(n * 16 + c) * 64 + (((g + 4 * kk) ^ (c & 7)) * 8)];
      f32x4 s[4][2] = {};
#pragma unroll
      for (int kk = 0; kk < 2; ++kk)
#pragma unroll
        for (int n = 0; n < 4; ++n)
#pragma unroll
          for (int m = 0; m < 2; ++m)
            s[n][m] = __builtin_amdgcn_mfma_f32_16x16x32_bf16(kf[n][kk], qf[m][kk], s[n][m], 0, 0, 0);

      const bool need_mask = (kv0 + 63 > qw);  // only diagonal tiles mask
#pragma unroll
      for (int m = 0; m < 2; ++m) {
        const int qg = qw + m * 16 + c;
        if (need_mask) {
#pragma unroll
          for (int n = 0; n < 4; ++n)
#pragma unroll
            for (int jj = 0; jj < 4; ++jj)
              if (kv0 + n * 16 + g * 4 + jj > qg) s[n][m][jj] = -__builtin_inff();
        }
        // lane-local max over 16 k-values, then reduce across 4 g-groups
        float mloc = fmaxf(fmaxf(s[0][m][0], s[0][m][1]), fmaxf(s[0][m][2], s[0][m][3]));
#pragma unroll
        for (int n = 1; n < 4; ++n)
          mloc = fmaxf(mloc, fmaxf(fmaxf(s[n][m][0], s[n][m][1]), fmaxf(s[n][m][2], s[n][m][3])));
        mloc = fmaxf(mloc, __shfl_xor(mloc, 16));
        mloc = fmaxf(mloc, __shfl_xor(mloc, 32));
        float mnew = fmaxf(mstate[m], mloc);
        float alpha = __expf(mstate[m] - mnew);  // first tile: exp(-inf)=0, harmless
        float lsum = 0.f;
#pragma unroll
        for (int n = 0; n < 4; ++n) {
          float p0 = __expf(s[n][m][0] - mnew);
          float p1 = __expf(s[n][m][1] - mnew);
          float p2 = __expf(s[n][m][2] - mnew);
          float p3 = __expf(s[n][m][3] - mnew);
          lsum += (p0 + p1) + (p2 + p3);
          ushort4 pk = make_ushort4(f2bf(p0), f2bf(p1), f2bf(p2), f2bf(p3));
          // P[q=m*16+c][k=n*16+g*4+jj], 16B-chunk XOR swizzle by row&7
          *(ushort4*)&pw[(m * 16 + c) * 64 + (((n * 2 + (g >> 1)) ^ (c & 7)) * 8) + (g & 1) * 4] = pk;
        }
        lsum += __shfl_xor(lsum, 16);
        lsum += __shfl_xor(lsum, 32);
        lstate[m] = lstate[m] * alpha + lsum;
        mstate[m] = mnew;
#pragma unroll
        for (int d = 0; d < 4; ++d)
#pragma unroll
          for (int jj = 0; jj < 4; ++jj) ot[d][m][jj] *= alpha;  // q col-mapped: no shfl
      }

      // ---- O^T += V^T P^T  (A = V^T rows d, B = P rows q)
      bf16x8 vf[4][2], pf[2][2];
#pragma unroll
      for (int d = 0; d < 4; ++d)
#pragma unroll
        for (int kk = 0; kk < 2; ++kk)
          vf[d][kk] = *(const bf16x8*)&Vl[cur][(d * 16 + c) * 64 + (((g + 4 * kk) ^ (c & 7)) * 8)];
#pragma unroll
      for (int m = 0; m < 2; ++m)
#pragma unroll
        for (int kk = 0; kk < 2; ++kk)
          pf[m][kk] = *(const bf16x8*)&pw[(m * 16 + c) * 64 + (((g + 4 * kk) ^ (c & 7)) * 8)];
#pragma unroll
      for (int kk = 0; kk < 2; ++kk)
#pragma unroll
        for (int d = 0; d < 4; ++d)
#pragma unroll
          for (int m = 0; m < 2; ++m)
            ot[d][m] = __builtin_amdgcn_mfma_f32_16x16x32_bf16(vf[d][kk], pf[m][kk], ot[d][m], 0, 0, 0);
    }
    __syncthreads();  // drains vmcnt: next tile staged; all waves done with cur
    cur ^= 1;
  }

  // ---- epilogue: O[q][d] = O^T/l, 8B packed stores (d contiguous per lane)
#pragma unroll
  for (int m = 0; m < 2; ++m) {
    float inv = 1.0f / lstate[m];
#pragma unroll
    for (int d = 0; d < 4; ++d) {
      ushort4 o4 = make_ushort4(f2bf(ot[d][m][0] * inv), f2bf(ot[d][m][1] * inv),
                                f2bf(ot[d][m][2] * inv), f2bf(ot[d][m][3] * inv));
      *(ushort4*)&O[(rowbase + qw + m * 16 + c) * D_MODEL + hcol + d * 16 + g * 4] = o4;
    }
  }
}

// ---------------------------------------------------------------- launch
extern "C" void kernel_launch(void* const* d_in, const int* in_sizes, int n_in,
                              void* d_out, int out_size, void* d_ws, size_t ws_size,
                              hipStream_t stream) {
  const float* x  = (const float*)d_in[0];
  const float* Wq = (const float*)d_in[1];
  const float* Wk = (const float*)d_in[2];
  const float* Wv = (const float*)d_in[3];
  const float* Wo = (const float*)d_in[4];
  float* out = (float*)d_out;

  u16* ws  = (u16*)d_ws;
  u16* xb  = ws;
  u16* wqb = xb + (size_t)NTOK * D_MODEL;
  u16* wkb = wqb + (size_t)D_MODEL * D_MODEL;
  u16* wvb = wkb + (size_t)D_MODEL * D_MODEL;
  u16* wob = wvb + (size_t)D_MODEL * D_MODEL;
  u16* Qb  = wob + (size_t)D_MODEL * D_MODEL;
  u16* Kb  = Qb + (size_t)NTOK * D_MODEL;
  u16* Vb  = Kb + (size_t)NTOK * D_MODEL;   // holds per-head V^T [B*H*64][SEQ]
  u16* Ob  = xb;  // reuse x's bf16 buffer after projections

  cvt_f32_bf16<<<(NTOK * D_MODEL / 4) / 256, 256, 0, stream>>>(x, xb, NTOK * D_MODEL / 4);
  cvt_f32_bf16<<<(D_MODEL * D_MODEL / 4) / 256, 256, 0, stream>>>(Wq, wqb, D_MODEL * D_MODEL / 4);
  cvt_f32_bf16<<<(D_MODEL * D_MODEL / 4) / 256, 256, 0, stream>>>(Wk, wkb, D_MODEL * D_MODEL / 4);
  cvt_f32_bf16<<<(D_MODEL * D_MODEL / 4) / 256, 256, 0, stream>>>(Wv, wvb, D_MODEL * D_MODEL / 4);
  cvt_f32_bf16<<<(D_MODEL * D_MODEL / 4) / 256, 256, 0, stream>>>(Wo, wob, D_MODEL * D_MODEL / 4);

  dim3 gproj(D_MODEL / 128, NTOK / 128);  // (8, 64)
  gemm_bt<3><<<gproj, 256, 0, stream>>>(xb, wqb, Qb, NTOK, D_MODEL, D_MODEL);  // Q, pre-scaled
  gemm_bt<1><<<gproj, 256, 0, stream>>>(xb, wkb, Kb, NTOK, D_MODEL, D_MODEL);  // K
  gemm_bt<2><<<gproj, 256, 0, stream>>>(xb, wvb, Vb, NTOK, D_MODEL, D_MODEL);  // V -> per-head V^T

  attn_fwd<<<dim3(SEQ / 128 * BATCH * NHEADS), 256, 0, stream>>>(Qb, Kb, Vb, Ob);

  gemm_bt<0><<<gproj, 256, 0, stream>>>(Ob, wob, out, NTOK, D_MODEL, D_MODEL);
}

// Round 3
// 207.666 us; speedup vs baseline: 1.9917x; 1.1034x over previous
//
#include <hip/hip_runtime.h>
#include <hip/hip_bf16.h>
#include <stdint.h>

// Problem constants
#define D_MODEL 1024
#define NHEADS  16
#define DKH     64
#define BATCH   4
#define SEQ     2048
#define NTOK    (BATCH * SEQ)   // 8192

typedef unsigned short u16;
using bf16x8 = __attribute__((ext_vector_type(8))) short;   // 8 bf16 = 4 VGPR (MFMA A/B frag)
using f32x4  = __attribute__((ext_vector_type(4))) float;   // MFMA C/D frag

// async global->LDS, 16B per lane; LDS dest is wave-uniform base (+lane*16 by HW)
#define GLD16(g, l)                                                            \
  __builtin_amdgcn_global_load_lds(                                            \
      (const __attribute__((address_space(1))) void*)(g),                      \
      (__attribute__((address_space(3))) void*)(l), 16, 0, 0)

__device__ inline u16 f2bf(float f) {
  __hip_bfloat16 h = __float2bfloat16(f);
  return __builtin_bit_cast(u16, h);
}

// ---------------------------------------------------------------- fused converts
__global__ __launch_bounds__(256) void cvt_all(const float* __restrict__ x,
                                               const float* __restrict__ wq,
                                               const float* __restrict__ wk,
                                               const float* __restrict__ wv,
                                               const float* __restrict__ wo,
                                               u16* xb, u16* wqb, u16* wkb, u16* wvb, u16* wob) {
  const int XC = NTOK * D_MODEL / 4;      // 2097152
  const int WC = D_MODEL * D_MODEL / 4;   // 262144
  const int total = XC + 4 * WC;
  for (int i = blockIdx.x * 256 + threadIdx.x; i < total; i += gridDim.x * 256) {
    const float4* s; ushort4* d; int j;
    if (i < XC)              { s = (const float4*)x;  d = (ushort4*)xb;  j = i; }
    else if (i < XC + WC)    { s = (const float4*)wq; d = (ushort4*)wqb; j = i - XC; }
    else if (i < XC + 2*WC)  { s = (const float4*)wk; d = (ushort4*)wkb; j = i - XC - WC; }
    else if (i < XC + 3*WC)  { s = (const float4*)wv; d = (ushort4*)wvb; j = i - XC - 2*WC; }
    else                     { s = (const float4*)wo; d = (ushort4*)wob; j = i - XC - 3*WC; }
    float4 v = s[j];
    d[j] = make_ushort4(f2bf(v.x), f2bf(v.y), f2bf(v.z), f2bf(v.w));
  }
}

// ---------------------------------------------------------------- fused QKV projection
// A [NTOK,D] bf16; Bq/Bk/Bv [D,D] bf16 (nn.Linear layout, C = A*B^T).
// z=0: Q out, scaled 0.125 (exact). z=1: K out. z=2: V out transposed per-head.
__global__ __launch_bounds__(256) void gemm_qkv(const u16* __restrict__ A,
                                                const u16* __restrict__ Bq,
                                                const u16* __restrict__ Bk,
                                                const u16* __restrict__ Bv,
                                                u16* __restrict__ Qo,
                                                u16* __restrict__ Ko,
                                                u16* __restrict__ Vo) {
  __shared__ u16 As[128 * 64];
  __shared__ u16 Bs[128 * 64];
  const int z = blockIdx.z;
  const u16* __restrict__ Bp = z == 0 ? Bq : (z == 1 ? Bk : Bv);
  const int t = threadIdx.x, lane = t & 63, wave = t >> 6;
  const int wr = wave >> 1, wc = wave & 1;
  const int frow = lane & 15, fk = (lane >> 4) * 8;
  const int bM = blockIdx.y * 128, bN = blockIdx.x * 128;

  f32x4 acc[4][4] = {};

  for (int k0 = 0; k0 < D_MODEL; k0 += 64) {
    __syncthreads();
#pragma unroll
    for (int p = 0; p < 4; ++p) {
      int chunk = p * 256 + t;
      int r = chunk >> 3, cc = chunk & 7;
      GLD16(A + (size_t)(bM + r) * D_MODEL + k0 + cc * 8, As + (size_t)(p * 256 + (t & ~63)) * 8);
      GLD16(Bp + (size_t)(bN + r) * D_MODEL + k0 + cc * 8, Bs + (size_t)(p * 256 + (t & ~63)) * 8);
    }
    __syncthreads();

    bf16x8 a[2][4], b[2][4];
#pragma unroll
    for (int kk = 0; kk < 2; ++kk) {
#pragma unroll
      for (int m = 0; m < 4; ++m)
        a[kk][m] = *(const bf16x8*)&As[(wr * 64 + m * 16 + frow) * 64 + kk * 32 + fk];
#pragma unroll
      for (int n = 0; n < 4; ++n)
        b[kk][n] = *(const bf16x8*)&Bs[(wc * 64 + n * 16 + frow) * 64 + kk * 32 + fk];
    }
#pragma unroll
    for (int kk = 0; kk < 2; ++kk)
#pragma unroll
      for (int m = 0; m < 4; ++m)
#pragma unroll
        for (int n = 0; n < 4; ++n)
          acc[m][n] = __builtin_amdgcn_mfma_f32_16x16x32_bf16(a[kk][m], b[kk][n], acc[m][n], 0, 0, 0);
  }

  const int r0 = bM + wr * 64 + (lane >> 4) * 4;
  const int c0 = bN + wc * 64 + (lane & 15);
  if (z == 2) {
#pragma unroll
    for (int m = 0; m < 4; ++m)
#pragma unroll
      for (int n = 0; n < 4; ++n) {
        int r = r0 + m * 16;   // token (4-aligned, j stays in one batch)
        int cc = c0 + n * 16;  // d_model col
        size_t off = ((size_t)(r >> 11) * D_MODEL + cc) * SEQ + (r & (SEQ - 1));
        *(ushort4*)(Vo + off) = make_ushort4(f2bf(acc[m][n][0]), f2bf(acc[m][n][1]),
                                             f2bf(acc[m][n][2]), f2bf(acc[m][n][3]));
      }
  } else {
    u16* C = z ? Ko : Qo;
    const float sc = z ? 1.0f : 0.125f;  // 1/sqrt(Dk), exact in bf16
#pragma unroll
    for (int m = 0; m < 4; ++m)
#pragma unroll
      for (int n = 0; n < 4; ++n)
#pragma unroll
        for (int j = 0; j < 4; ++j)
          C[(size_t)(r0 + m * 16 + j) * D_MODEL + (c0 + n * 16)] = f2bf(acc[m][n][j] * sc);
  }
}

// ---------------------------------------------------------------- output projection C = A*B^T, f32 out
__global__ __launch_bounds__(256) void gemm_out(const u16* __restrict__ A,
                                                const u16* __restrict__ B,
                                                float* __restrict__ C) {
  __shared__ u16 As[128 * 64];
  __shared__ u16 Bs[128 * 64];
  const int t = threadIdx.x, lane = t & 63, wave = t >> 6;
  const int wr = wave >> 1, wc = wave & 1;
  const int frow = lane & 15, fk = (lane >> 4) * 8;
  const int bM = blockIdx.y * 128, bN = blockIdx.x * 128;

  f32x4 acc[4][4] = {};

  for (int k0 = 0; k0 < D_MODEL; k0 += 64) {
    __syncthreads();
#pragma unroll
    for (int p = 0; p < 4; ++p) {
      int chunk = p * 256 + t;
      int r = chunk >> 3, cc = chunk & 7;
      GLD16(A + (size_t)(bM + r) * D_MODEL + k0 + cc * 8, As + (size_t)(p * 256 + (t & ~63)) * 8);
      GLD16(B + (size_t)(bN + r) * D_MODEL + k0 + cc * 8, Bs + (size_t)(p * 256 + (t & ~63)) * 8);
    }
    __syncthreads();

    bf16x8 a[2][4], b[2][4];
#pragma unroll
    for (int kk = 0; kk < 2; ++kk) {
#pragma unroll
      for (int m = 0; m < 4; ++m)
        a[kk][m] = *(const bf16x8*)&As[(wr * 64 + m * 16 + frow) * 64 + kk * 32 + fk];
#pragma unroll
      for (int n = 0; n < 4; ++n)
        b[kk][n] = *(const bf16x8*)&Bs[(wc * 64 + n * 16 + frow) * 64 + kk * 32 + fk];
    }
#pragma unroll
    for (int kk = 0; kk < 2; ++kk)
#pragma unroll
      for (int m = 0; m < 4; ++m)
#pragma unroll
        for (int n = 0; n < 4; ++n)
          acc[m][n] = __builtin_amdgcn_mfma_f32_16x16x32_bf16(a[kk][m], b[kk][n], acc[m][n], 0, 0, 0);
  }

  const int r0 = bM + wr * 64 + (lane >> 4) * 4;
  const int c0 = bN + wc * 64 + (lane & 15);
#pragma unroll
  for (int m = 0; m < 4; ++m)
#pragma unroll
    for (int n = 0; n < 4; ++n)
#pragma unroll
      for (int j = 0; j < 4; ++j)
        C[(size_t)(r0 + m * 16 + j) * D_MODEL + (c0 + n * 16)] = acc[m][n][j];
}

// ---------------------------------------------------------------- flash attention (causal)
// Q (pre-scaled 0.125), K: bf16 [NTOK, D_MODEL]; Vt: bf16 [B*H*64][SEQ]; O: bf16 [NTOK, D_MODEL].
// Block = 128 q rows of one (b,h); 4 waves x 32 q; KV tile 64, double-buffered.
// Swapped QK^T; per-m P pipeline through one 16x64 wave-private LDS buffer; defer-max.
__global__ __launch_bounds__(256) void attn_fwd(const u16* __restrict__ Q,
                                                const u16* __restrict__ K,
                                                const u16* __restrict__ Vt,
                                                u16* __restrict__ O) {
  __shared__ u16 Kl[2][64 * 64];   // 16 KB
  __shared__ u16 Vl[2][64 * 64];   // 16 KB
  __shared__ u16 Pl[4][16 * 64];   // 8 KB -> 40 KB total, 4 blocks/CU

  const int t = threadIdx.x, lane = t & 63, wave = t >> 6;
  const int c = lane & 15, g = lane >> 4;
  const int bh = blockIdx.x & 63;           // bh fastest: same-KV blocks share an XCD
  const int qtile = 15 - (blockIdx.x >> 6); // heavy-first
  const int q0 = qtile * 128;
  const size_t rowbase = (size_t)(bh >> 4) * SEQ;
  const int hcol = (bh & 15) * DKH;
  const int qw = q0 + wave * 32;
  u16* pw = Pl[wave];
  const int nit = qtile * 2 + 2;

  auto stage = [&](int buf, int kv0) {
#pragma unroll
    for (int p = 0; p < 2; ++p) {
      int chunk = p * 256 + t;
      int r = chunk >> 3, cc = chunk & 7;
      int cs = cc ^ (r & 7);  // pre-swizzled global source; LDS linear
      GLD16(K + (rowbase + kv0 + r) * D_MODEL + hcol + cs * 8,
            &Kl[buf][(size_t)(p * 256 + (t & ~63)) * 8]);
      GLD16(Vt + ((size_t)bh * DKH + r) * SEQ + kv0 + cs * 8,
            &Vl[buf][(size_t)(p * 256 + (t & ~63)) * 8]);
    }
  };

  stage(0, 0);

  bf16x8 qf[2][2];
#pragma unroll
  for (int m = 0; m < 2; ++m)
#pragma unroll
    for (int kk = 0; kk < 2; ++kk)
      qf[m][kk] = *(const bf16x8*)&Q[(rowbase + qw + m * 16 + c) * D_MODEL + hcol + kk * 32 + g * 8];

  f32x4 ot[4][2] = {};              // O^T[d_local][q]
  float mstate[2] = {-__builtin_inff(), -__builtin_inff()};
  float lstate[2] = {0.f, 0.f};

  __syncthreads();
  int cur = 0;
  for (int it = 0; it < nit; ++it) {
    const int kv0 = it * 64;
    if (it + 1 < nit) stage(cur ^ 1, kv0 + 64);

    if (kv0 <= qw + 31) {  // wave-uniform causal participation
      // ---- S^T = K Q^T
      bf16x8 kf[4][2];
#pragma unroll
      for (int n = 0; n < 4; ++n)
#pragma unroll
        for (int kk = 0; kk < 2; ++kk)
          kf[n][kk] = *(const bf16x8*)&Kl[cur][(n * 16 + c) * 64 + (((g + 4 * kk) ^ (c & 7)) * 8)];
      f32x4 s[4][2] = {};
      __builtin_amdgcn_s_setprio(1);
#pragma unroll
      for (int kk = 0; kk < 2; ++kk)
#pragma unroll
        for (int n = 0; n < 4; ++n)
#pragma unroll
          for (int m = 0; m < 2; ++m)
            s[n][m] = __builtin_amdgcn_mfma_f32_16x16x32_bf16(kf[n][kk], qf[m][kk], s[n][m], 0, 0, 0);
      __builtin_amdgcn_s_setprio(0);

      // V^T fragments early: ds_read latency hides under softmax VALU
      bf16x8 vf[4][2];
#pragma unroll
      for (int d = 0; d < 4; ++d)
#pragma unroll
        for (int kk = 0; kk < 2; ++kk)
          vf[d][kk] = *(const bf16x8*)&Vl[cur][(d * 16 + c) * 64 + (((g + 4 * kk) ^ (c & 7)) * 8)];

      const bool need_mask = (kv0 + 63 > qw);
#pragma unroll
      for (int m = 0; m < 2; ++m) {
        const int qg = qw + m * 16 + c;
        if (need_mask) {
#pragma unroll
          for (int n = 0; n < 4; ++n)
#pragma unroll
            for (int jj = 0; jj < 4; ++jj)
              if (kv0 + n * 16 + g * 4 + jj > qg) s[n][m][jj] = -__builtin_inff();
        }
        // tile max for this q (lane-local 16 values, then cross-g reduce)
        float pmax = fmaxf(fmaxf(s[0][m][0], s[0][m][1]), fmaxf(s[0][m][2], s[0][m][3]));
#pragma unroll
        for (int n = 1; n < 4; ++n)
          pmax = fmaxf(pmax, fmaxf(fmaxf(s[n][m][0], s[n][m][1]), fmaxf(s[n][m][2], s[n][m][3])));
        pmax = fmaxf(pmax, __shfl_xor(pmax, 16));
        pmax = fmaxf(pmax, __shfl_xor(pmax, 32));
        // defer-max (T13): only rescale when max grew past threshold; P bounded by e^8
        if (__any(pmax > mstate[m] + 8.0f)) {
          float mnew = fmaxf(mstate[m], pmax);
          float al = __expf(mstate[m] - mnew);  // first tile: exp(-inf)=0
          mstate[m] = mnew;
          lstate[m] *= al;
#pragma unroll
          for (int d = 0; d < 4; ++d)
#pragma unroll
            for (int jj = 0; jj < 4; ++jj) ot[d][m][jj] *= al;
        }
        const float mm = mstate[m];
        float lsum = 0.f;
#pragma unroll
        for (int n = 0; n < 4; ++n) {
          float p0 = __expf(s[n][m][0] - mm);
          float p1 = __expf(s[n][m][1] - mm);
          float p2 = __expf(s[n][m][2] - mm);
          float p3 = __expf(s[n][m][3] - mm);
          lsum += (p0 + p1) + (p2 + p3);
          // P[q=c][k=n*16+g*4+jj], 16B-chunk XOR swizzle by row&7
          *(ushort4*)&pw[c * 64 + (((n * 2 + (g >> 1)) ^ (c & 7)) * 8) + (g & 1) * 4] =
              make_ushort4(f2bf(p0), f2bf(p1), f2bf(p2), f2bf(p3));
        }
        lsum += __shfl_xor(lsum, 16);
        lsum += __shfl_xor(lsum, 32);
        lstate[m] += lsum;

        // ---- O^T[.,m] += V^T P^T (wave-private LDS roundtrip; in-order DS ops, no barrier)
        bf16x8 pf[2];
#pragma unroll
        for (int kk = 0; kk < 2; ++kk)
          pf[kk] = *(const bf16x8*)&pw[c * 64 + (((g + 4 * kk) ^ (c & 7)) * 8)];
        __builtin_amdgcn_s_setprio(1);
#pragma unroll
        for (int kk = 0; kk < 2; ++kk)
#pragma unroll
          for (int d = 0; d < 4; ++d)
            ot[d][m] = __builtin_amdgcn_mfma_f32_16x16x32_bf16(vf[d][kk], pf[kk], ot[d][m], 0, 0, 0);
        __builtin_amdgcn_s_setprio(0);
      }
    }
    __syncthreads();
    cur ^= 1;
  }

  // ---- epilogue: O[q][d] = O^T/l
#pragma unroll
  for (int m = 0; m < 2; ++m) {
    float inv = 1.0f / lstate[m];
#pragma unroll
    for (int d = 0; d < 4; ++d) {
      ushort4 o4 = make_ushort4(f2bf(ot[d][m][0] * inv), f2bf(ot[d][m][1] * inv),
                                f2bf(ot[d][m][2] * inv), f2bf(ot[d][m][3] * inv));
      *(ushort4*)&O[(rowbase + qw + m * 16 + c) * D_MODEL + hcol + d * 16 + g * 4] = o4;
    }
  }
}

// ---------------------------------------------------------------- launch
extern "C" void kernel_launch(void* const* d_in, const int* in_sizes, int n_in,
                              void* d_out, int out_size, void* d_ws, size_t ws_size,
                              hipStream_t stream) {
  const float* x  = (const float*)d_in[0];
  const float* Wq = (const float*)d_in[1];
  const float* Wk = (const float*)d_in[2];
  const float* Wv = (const float*)d_in[3];
  const float* Wo = (const float*)d_in[4];
  float* out = (float*)d_out;

  u16* ws  = (u16*)d_ws;
  u16* xb  = ws;
  u16* wqb = xb + (size_t)NTOK * D_MODEL;
  u16* wkb = wqb + (size_t)D_MODEL * D_MODEL;
  u16* wvb = wkb + (size_t)D_MODEL * D_MODEL;
  u16* wob = wvb + (size_t)D_MODEL * D_MODEL;
  u16* Qb  = wob + (size_t)D_MODEL * D_MODEL;
  u16* Kb  = Qb + (size_t)NTOK * D_MODEL;
  u16* Vb  = Kb + (size_t)NTOK * D_MODEL;   // per-head V^T [B*H*64][SEQ]
  u16* Ob  = xb;  // reuse x's bf16 buffer after projections

  cvt_all<<<2048, 256, 0, stream>>>(x, Wq, Wk, Wv, Wo, xb, wqb, wkb, wvb, wob);

  gemm_qkv<<<dim3(D_MODEL / 128, NTOK / 128, 3), 256, 0, stream>>>(xb, wqb, wkb, wvb, Qb, Kb, Vb);

  attn_fwd<<<dim3(SEQ / 128 * BATCH * NHEADS), 256, 0, stream>>>(Qb, Kb, Vb, Ob);

  gemm_out<<<dim3(D_MODEL / 128, NTOK / 128), 256, 0, stream>>>(Ob, wob, out);
}